// Round 4
// baseline (127.191 us; speedup 1.0000x reference)
//
#include <hip/hip_runtime.h>
#include <stdint.h>

// Problem constants
constexpr int C_IN  = 512;
constexpr int HW    = 784;            // 28*28
constexpr int NB    = 32;
constexpr int M_TOT = NB * HW;        // 25088
constexpr int N_TOT = 2000;
constexpr int NPAD  = 2048;
constexpr int IMG_STRIDE = C_IN * HW;
constexpr int OUT_BATCH  = N_TOT * HW;

// GEMM tiling: 256x256, BK=32, 16 K-tiles, 4-buffer ring, prefetch 3
constexpr int TBM = 256;
constexpr int TBN = 256;
constexpr int NKT = C_IN / 32;        // 16

typedef __attribute__((ext_vector_type(8))) short bf16x8;
typedef __attribute__((ext_vector_type(4))) float f32x4;

__device__ __forceinline__ uint16_t f2bf(float f) {
    union { float f; uint32_t u; } x; x.f = f;
    return (uint16_t)((x.u + 0x8000u) >> 16);
}

__device__ __forceinline__ void gload_lds16(const void* g, void* l) {
    __builtin_amdgcn_global_load_lds(
        (const __attribute__((address_space(1))) void*)g,
        (__attribute__((address_space(3))) void*)l, 16, 0, 0);
}

// ---------------------------------------------------------------------------
// prep_a: Abf[m][k] = bf16(input) transposed through LDS; fused s2[m]
__global__ __launch_bounds__(256) void prep_a_kernel(const float* __restrict__ in,
                                                     short* __restrict__ Abf,
                                                     float* __restrict__ s2) {
    __shared__ __align__(16) char T[64 * 512 * 2];
    __shared__ float red[16][64];

    const int t = threadIdx.x;
    const int q = t & 15;
    const int part = t >> 4;
    const int m0q = blockIdx.x * 64 + q * 4;
    const uint32_t b  = (uint32_t)m0q / 784u;
    const uint32_t hw = (uint32_t)m0q % 784u;
    const float* base = in + (size_t)b * IMG_STRIDE + hw;

    float4 acc = make_float4(0.f, 0.f, 0.f, 0.f);
    const int c0 = part * 32;
#pragma unroll 4
    for (int c = c0; c < c0 + 32; ++c) {
        float4 v = *(const float4*)(base + (size_t)c * HW);
        acc.x = fmaf(v.x, v.x, acc.x);
        acc.y = fmaf(v.y, v.y, acc.y);
        acc.z = fmaf(v.z, v.z, acc.z);
        acc.w = fmaf(v.w, v.w, acc.w);
        uint16_t vals[4] = { f2bf(v.x), f2bf(v.y), f2bf(v.z), f2bf(v.w) };
        const uint32_t by0 = (uint32_t)(q * 4) * 1024u + (uint32_t)c * 2u;
#pragma unroll
        for (int j = 0; j < 4; ++j) {
            uint32_t bb = by0 + (uint32_t)j * 1024u;
            bb ^= ((bb >> 12) & 7u) << 4;
            *(uint16_t*)(T + bb) = vals[j];
        }
    }
    red[part][q * 4 + 0] = acc.x;
    red[part][q * 4 + 1] = acc.y;
    red[part][q * 4 + 2] = acc.z;
    red[part][q * 4 + 3] = acc.w;
    __syncthreads();
    if (t < 64) {
        float s = 0.f;
#pragma unroll
        for (int p = 0; p < 16; ++p) s += red[p][t];
        s2[blockIdx.x * 64 + t] = s;
    }
    short* dst = Abf + (size_t)blockIdx.x * 64 * 512;
#pragma unroll
    for (int i = 0; i < 16; ++i) {
        const int idx = i * 256 + t;
        const int row = idx >> 6, ch = idx & 63;
        uint32_t bb = (uint32_t)row * 1024u + (uint32_t)ch * 16u;
        bb ^= ((bb >> 12) & 7u) << 4;
        bf16x8 v = *(bf16x8*)(T + bb);
        *(bf16x8*)(dst + (size_t)row * 512 + ch * 8) = v;
    }
}

// ---------------------------------------------------------------------------
// prep_w: Wbf[p][k] = bf16(w), rows >= N_TOT zeroed; fused w2[p]
__global__ __launch_bounds__(256) void prep_w_kernel(const float* __restrict__ w,
                                                     short* __restrict__ Wbf,
                                                     float* __restrict__ w2) {
    const int wv = threadIdx.x >> 6, lane = threadIdx.x & 63;
    const int p = blockIdx.x * 4 + wv;
    bf16x8 o = (bf16x8)0;
    float s = 0.f;
    if (p < N_TOT) {
        const float* base = w + (size_t)p * C_IN + lane * 8;
        float4 a = *(const float4*)base;
        float4 c = *(const float4*)(base + 4);
        s = a.x*a.x + a.y*a.y + a.z*a.z + a.w*a.w
          + c.x*c.x + c.y*c.y + c.z*c.z + c.w*c.w;
        o[0] = (short)f2bf(a.x); o[1] = (short)f2bf(a.y);
        o[2] = (short)f2bf(a.z); o[3] = (short)f2bf(a.w);
        o[4] = (short)f2bf(c.x); o[5] = (short)f2bf(c.y);
        o[6] = (short)f2bf(c.z); o[7] = (short)f2bf(c.w);
    }
    *(bf16x8*)(Wbf + (size_t)p * C_IN + lane * 8) = o;
#pragma unroll
    for (int off = 32; off; off >>= 1) s += __shfl_down(s, off);
    if (lane == 0) w2[p] = s;
}

// ---------------------------------------------------------------------------
// gemm4: 256x256 tile, BK=32, 4-buffer LDS ring, prefetch depth 3, counted
// vmcnt (never drains mid-loop), ONE barrier per K-tile, conflict-free slot
// swizzle (linear LDS dest + pre-swizzled global source), setprio on MFMA.
//
// LDS buffer b (32 KB): A 256 rows x 32k bf16 (64 B/row) at +0,
//                       B 256 rows x 32k at +16384.
// Slot swizzle: k-group g of row r stored at slot g ^ ((r>>1)&3).
__global__ __launch_bounds__(512, 2) void gemm4_kernel(const short* __restrict__ Abf,
                                                       const short* __restrict__ Wbf,
                                                       const float* __restrict__ s2,
                                                       const float* __restrict__ w2,
                                                       float* __restrict__ out) {
    __shared__ __align__(16) char smem[131072];   // 4 bufs x 32 KB

    const int t = threadIdx.x;
    const int wv = t >> 6, lane = t & 63;
    const int lr = lane & 15, lg = lane >> 4;

    // XCD mapping: bn = bid&7 -> each XCD owns one bn column (B panel L2-hot)
    const int orig = blockIdx.x;
    const int bn = orig & 7;
    const int bm = orig >> 3;

    const short* Ab = Abf + (size_t)bm * TBM * C_IN;
    const short* Bb = Wbf + (size_t)bn * TBN * C_IN;

    // ---- staging: wave wv instr j covers rows wv*32+j*16+(lane>>2), slot lane&3
    //      (LDS dest linear: base + lane*16). Source pre-swizzled:
    //      k-group g = (lane&3) ^ ((lane>>3)&3)
    const int srow = wv * 32 + (lane >> 2);
    const int sg   = (lane & 3) ^ ((lane >> 3) & 3);
    const short* AsrcL = Ab + (size_t)srow * C_IN + sg * 8;
    const short* BsrcL = Bb + (size_t)srow * C_IN + sg * 8;
    const int adst = wv * 2048;               // byte offset of wave's A rows

    // ---- wave -> output subtile (128m x 64n)
    const int wm = (wv >> 2) * 128;           // {0,128}
    const int wn = (wv & 3) * 64;             // {0,64,128,192}

    // ---- ds_read offsets: row r, slot lg^((lr>>1)&3); frag stride 1024 B
    const int slot  = lg ^ ((lr >> 1) & 3);
    const int abase = (wm + lr) * 64 + slot * 16;
    const int bbase = 16384 + (wn + lr) * 64 + slot * 16;

    f32x4 acc[8][4] = {};

#define STAGE(tt)                                                              \
    do {                                                                       \
        char* abuf_ = smem + ((tt) & 3) * 32768;                               \
        const short* As_ = AsrcL + (tt) * 32;                                  \
        const short* Bs_ = BsrcL + (tt) * 32;                                  \
        gload_lds16(As_,             abuf_ + adst);                            \
        gload_lds16(As_ + 16 * 512,  abuf_ + adst + 1024);                     \
        gload_lds16(Bs_,             abuf_ + 16384 + adst);                    \
        gload_lds16(Bs_ + 16 * 512,  abuf_ + 16384 + adst + 1024);             \
    } while (0)

    // prologue: issue stages for tiles 0,1,2 (12 loads in flight)
    STAGE(0);
    STAGE(1);
    STAGE(2);

#pragma unroll
    for (int kt = 0; kt < NKT; ++kt) {
        // entry gate: my stage(kt) landed; kt+1,kt+2 stay in flight
        if (kt <= NKT - 3)      asm volatile("s_waitcnt vmcnt(8)" ::: "memory");
        else if (kt == NKT - 2) asm volatile("s_waitcnt vmcnt(4)" ::: "memory");
        else                    asm volatile("s_waitcnt vmcnt(0)" ::: "memory");
        __builtin_amdgcn_sched_barrier(0);
        __builtin_amdgcn_s_barrier();      // all waves' stage(kt) landed;
        __builtin_amdgcn_sched_barrier(0); // buf (kt+3)&3 fully consumed (iter kt-1)

        if (kt + 3 < NKT) STAGE(kt + 3);   // into buffer freed at this barrier

        const char* buf = smem + (kt & 3) * 32768;
        bf16x8 bfrag[4], afrag[8];
#pragma unroll
        for (int n = 0; n < 4; ++n)
            bfrag[n] = *(const bf16x8*)(buf + bbase + n * 1024);
#pragma unroll
        for (int m = 0; m < 8; ++m)
            afrag[m] = *(const bf16x8*)(buf + abase + m * 1024);

        __builtin_amdgcn_s_setprio(1);
#pragma unroll
        for (int m = 0; m < 8; ++m)
#pragma unroll
            for (int n = 0; n < 4; ++n)
                acc[m][n] = __builtin_amdgcn_mfma_f32_16x16x32_bf16(
                    afrag[m], bfrag[n], acc[m][n], 0, 0, 0);
        __builtin_amdgcn_s_setprio(0);
    }
#undef STAGE

    // epilogue: relu(s2 - 2*acc + w2), float4 over 4 consecutive m (hw-contig)
#pragma unroll
    for (int m = 0; m < 8; ++m) {
        const int m_r = bm * TBM + wm + m * 16 + lg * 4;   // 4-aligned, 784%4==0
        const float4 s2v = *(const float4*)(s2 + m_r);
        const uint32_t ob  = (uint32_t)m_r / 784u;
        const uint32_t ohw = (uint32_t)m_r % 784u;
        float* obase = out + (size_t)ob * OUT_BATCH + ohw;
#pragma unroll
        for (int n = 0; n < 4; ++n) {
            const int n_o = bn * TBN + wn + n * 16 + lr;
            if (n_o < N_TOT) {
                const float wvv = w2[n_o];
                const f32x4 a = acc[m][n];
                float4 r;
                r.x = fmaxf(s2v.x - 2.f * a.x + wvv, 0.f);
                r.y = fmaxf(s2v.y - 2.f * a.y + wvv, 0.f);
                r.z = fmaxf(s2v.z - 2.f * a.z + wvv, 0.f);
                r.w = fmaxf(s2v.w - 2.f * a.w + wvv, 0.f);
                *(float4*)(obase + (size_t)n_o * HW) = r;
            }
        }
    }
}

// ---------------------------------------------------------------------------
extern "C" void kernel_launch(void* const* d_in, const int* in_sizes, int n_in,
                              void* d_out, int out_size, void* d_ws, size_t ws_size,
                              hipStream_t stream) {
    const float* in = (const float*)d_in[0];   // [32,512,28,28] fp32
    const float* w  = (const float*)d_in[1];   // [2000,512,1,1] fp32
    float* out = (float*)d_out;                // [32,2000,28,28] fp32

    const size_t offA  = 0;
    const size_t offW  = offA + (size_t)M_TOT * C_IN * sizeof(short);   // 25.7 MB
    const size_t offS2 = offW + (size_t)NPAD * C_IN * sizeof(short);    // +2.1 MB
    const size_t offW2 = offS2 + (size_t)M_TOT * sizeof(float);

    short* Abf = (short*)((char*)d_ws + offA);
    short* Wbf = (short*)((char*)d_ws + offW);
    float* s2  = (float*)((char*)d_ws + offS2);
    float* w2  = (float*)((char*)d_ws + offW2);

    prep_a_kernel<<<M_TOT / 64, 256, 0, stream>>>(in, Abf, s2);
    prep_w_kernel<<<NPAD / 4, 256, 0, stream>>>(w, Wbf, w2);

    // 98 m-tiles x 8 n-tiles; bn = bid&7 -> per-XCD bn column
    gemm4_kernel<<<98 * 8, 512, 0, stream>>>(Abf, Wbf, s2, w2, out);
}

// Round 5
// 109.554 us; speedup vs baseline: 1.1610x; 1.1610x over previous
//
#include <hip/hip_runtime.h>
#include <stdint.h>

// Problem constants
constexpr int C_IN  = 512;
constexpr int HW    = 784;            // 28*28
constexpr int NB    = 32;
constexpr int M_TOT = NB * HW;        // 25088
constexpr int N_TOT = 2000;
constexpr int NPAD  = 2048;
constexpr int IMG_STRIDE = C_IN * HW;
constexpr int OUT_BATCH  = N_TOT * HW;

// GEMM tiling: 128x128, BK=32, 16 K-tiles, ring-3 LDS, prefetch 2, 3 blocks/CU
constexpr int TBM = 128;
constexpr int TBN = 128;
constexpr int NKT = C_IN / 32;        // 16

typedef __attribute__((ext_vector_type(8))) short bf16x8;
typedef __attribute__((ext_vector_type(4))) float f32x4;

__device__ __forceinline__ uint16_t f2bf(float f) {
    union { float f; uint32_t u; } x; x.f = f;
    return (uint16_t)((x.u + 0x8000u) >> 16);
}

__device__ __forceinline__ void gload_lds16(const void* g, void* l) {
    __builtin_amdgcn_global_load_lds(
        (const __attribute__((address_space(1))) void*)g,
        (__attribute__((address_space(3))) void*)l, 16, 0, 0);
}

// ---------------------------------------------------------------------------
// prep_a: Abf[m][k] = bf16(input) transposed through LDS; fused s2[m]
__global__ __launch_bounds__(256) void prep_a_kernel(const float* __restrict__ in,
                                                     short* __restrict__ Abf,
                                                     float* __restrict__ s2) {
    __shared__ __align__(16) char T[64 * 512 * 2];
    __shared__ float red[16][64];

    const int t = threadIdx.x;
    const int q = t & 15;
    const int part = t >> 4;
    const int m0q = blockIdx.x * 64 + q * 4;
    const uint32_t b  = (uint32_t)m0q / 784u;
    const uint32_t hw = (uint32_t)m0q % 784u;
    const float* base = in + (size_t)b * IMG_STRIDE + hw;

    float4 acc = make_float4(0.f, 0.f, 0.f, 0.f);
    const int c0 = part * 32;
#pragma unroll 4
    for (int c = c0; c < c0 + 32; ++c) {
        float4 v = *(const float4*)(base + (size_t)c * HW);
        acc.x = fmaf(v.x, v.x, acc.x);
        acc.y = fmaf(v.y, v.y, acc.y);
        acc.z = fmaf(v.z, v.z, acc.z);
        acc.w = fmaf(v.w, v.w, acc.w);
        uint16_t vals[4] = { f2bf(v.x), f2bf(v.y), f2bf(v.z), f2bf(v.w) };
        const uint32_t by0 = (uint32_t)(q * 4) * 1024u + (uint32_t)c * 2u;
#pragma unroll
        for (int j = 0; j < 4; ++j) {
            uint32_t bb = by0 + (uint32_t)j * 1024u;
            bb ^= ((bb >> 12) & 7u) << 4;
            *(uint16_t*)(T + bb) = vals[j];
        }
    }
    red[part][q * 4 + 0] = acc.x;
    red[part][q * 4 + 1] = acc.y;
    red[part][q * 4 + 2] = acc.z;
    red[part][q * 4 + 3] = acc.w;
    __syncthreads();
    if (t < 64) {
        float s = 0.f;
#pragma unroll
        for (int p = 0; p < 16; ++p) s += red[p][t];
        s2[blockIdx.x * 64 + t] = s;
    }
    short* dst = Abf + (size_t)blockIdx.x * 64 * 512;
#pragma unroll
    for (int i = 0; i < 16; ++i) {
        const int idx = i * 256 + t;
        const int row = idx >> 6, ch = idx & 63;
        uint32_t bb = (uint32_t)row * 1024u + (uint32_t)ch * 16u;
        bb ^= ((bb >> 12) & 7u) << 4;
        bf16x8 v = *(bf16x8*)(T + bb);
        *(bf16x8*)(dst + (size_t)row * 512 + ch * 8) = v;
    }
}

// ---------------------------------------------------------------------------
// prep_w: Wbf[p][k] = bf16(w), rows >= N_TOT zeroed; fused w2[p]
__global__ __launch_bounds__(256) void prep_w_kernel(const float* __restrict__ w,
                                                     short* __restrict__ Wbf,
                                                     float* __restrict__ w2) {
    const int wv = threadIdx.x >> 6, lane = threadIdx.x & 63;
    const int p = blockIdx.x * 4 + wv;
    bf16x8 o = (bf16x8)0;
    float s = 0.f;
    if (p < N_TOT) {
        const float* base = w + (size_t)p * C_IN + lane * 8;
        float4 a = *(const float4*)base;
        float4 c = *(const float4*)(base + 4);
        s = a.x*a.x + a.y*a.y + a.z*a.z + a.w*a.w
          + c.x*c.x + c.y*c.y + c.z*c.z + c.w*c.w;
        o[0] = (short)f2bf(a.x); o[1] = (short)f2bf(a.y);
        o[2] = (short)f2bf(a.z); o[3] = (short)f2bf(a.w);
        o[4] = (short)f2bf(c.x); o[5] = (short)f2bf(c.y);
        o[6] = (short)f2bf(c.z); o[7] = (short)f2bf(c.w);
    }
    *(bf16x8*)(Wbf + (size_t)p * C_IN + lane * 8) = o;
#pragma unroll
    for (int off = 32; off; off >>= 1) s += __shfl_down(s, off);
    if (lane == 0) w2[p] = s;
}

// ---------------------------------------------------------------------------
// gemm5: 128x128 tile, BK=32, ring-3 LDS (48 KB -> 3 blocks/CU), prefetch 2,
// counted vmcnt (never drains mid-loop), one barrier per K-tile, conflict-free
// slot swizzle (linear LDS dest + pre-swizzled global source), setprio on MFMA.
//
// LDS buffer b (16 KB): A 128 rows x 32k bf16 (64 B/row) at +0,
//                       B 128 rows x 32k at +8192.
// Slot swizzle: k-group g of row r stored at slot g ^ ((r>>1)&3).
__global__ __launch_bounds__(256, 3) void gemm5_kernel(const short* __restrict__ Abf,
                                                       const short* __restrict__ Wbf,
                                                       const float* __restrict__ s2,
                                                       const float* __restrict__ w2,
                                                       float* __restrict__ out) {
    __shared__ __align__(16) char smem[49152];    // 3 bufs x 16 KB

    const int t = threadIdx.x;
    const int wv = t >> 6, lane = t & 63;
    const int lr = lane & 15, lg = lane >> 4;

    const int bid = blockIdx.x;
    const int bn = bid & 15;               // 16 n-tiles (consecutive bids share bm)
    const int bm = bid >> 4;               // 196 m-tiles

    const short* Ab = Abf + (size_t)bm * TBM * C_IN;
    const short* Bb = Wbf + (size_t)bn * TBN * C_IN;

    // ---- staging: wave wv instr j covers rows wv*32+j*16+(lane>>2), slot lane&3
    //      (LDS dest linear: base + lane*16). Source pre-swizzled:
    //      k-group g = (lane&3) ^ ((lane>>3)&3)   [= slot ^ ((row>>1)&3)]
    const int srow = wv * 32 + (lane >> 2);
    const int sg   = (lane & 3) ^ ((lane >> 3) & 3);
    const short* AsrcL = Ab + (size_t)srow * C_IN + sg * 8;
    const short* BsrcL = Bb + (size_t)srow * C_IN + sg * 8;
    const int adst = wv * 2048;            // + j*1024 + lane*16

    // ---- wave -> output subtile (64m x 64n)
    const int wm = (wv >> 1) * 64;         // {0,64}
    const int wn = (wv & 1) * 64;          // {0,64}

    // ---- ds_read offsets: row r, slot lg^((lr>>1)&3); frag stride 1024 B
    const int slot  = lg ^ ((lr >> 1) & 3);
    const int abase = (wm + lr) * 64 + slot * 16;
    const int bbase = 8192 + (wn + lr) * 64 + slot * 16;

    f32x4 acc[4][4] = {};

#define STAGE(tt)                                                              \
    do {                                                                       \
        char* buf_ = smem + ((tt) % 3) * 16384;                                \
        const short* As_ = AsrcL + (tt) * 32;                                  \
        const short* Bs_ = BsrcL + (tt) * 32;                                  \
        gload_lds16(As_,             buf_ + adst);                             \
        gload_lds16(As_ + 16 * 512,  buf_ + adst + 1024);                      \
        gload_lds16(Bs_,             buf_ + 8192 + adst);                      \
        gload_lds16(Bs_ + 16 * 512,  buf_ + 8192 + adst + 1024);               \
    } while (0)

    // prologue: issue stages for tiles 0,1 (8 loads in flight)
    STAGE(0);
    STAGE(1);

#pragma unroll
    for (int kt = 0; kt < NKT; ++kt) {
        // entry gate: my stage(kt) landed; stage(kt+1) stays in flight
        if (kt < NKT - 1) asm volatile("s_waitcnt vmcnt(4)" ::: "memory");
        else              asm volatile("s_waitcnt vmcnt(0)" ::: "memory");
        __builtin_amdgcn_sched_barrier(0);
        __builtin_amdgcn_s_barrier();      // all waves' stage(kt) landed;
        __builtin_amdgcn_sched_barrier(0); // buf (kt+2)%3 fully consumed (iter kt-1)

        if (kt + 2 < NKT) STAGE(kt + 2);   // into buffer freed at this barrier

        const char* buf = smem + (kt % 3) * 16384;
        bf16x8 bfrag[4], afrag[4];
#pragma unroll
        for (int n = 0; n < 4; ++n)
            bfrag[n] = *(const bf16x8*)(buf + bbase + n * 1024);
#pragma unroll
        for (int m = 0; m < 4; ++m)
            afrag[m] = *(const bf16x8*)(buf + abase + m * 1024);

        __builtin_amdgcn_s_setprio(1);
#pragma unroll
        for (int m = 0; m < 4; ++m)
#pragma unroll
            for (int n = 0; n < 4; ++n)
                acc[m][n] = __builtin_amdgcn_mfma_f32_16x16x32_bf16(
                    afrag[m], bfrag[n], acc[m][n], 0, 0, 0);
        __builtin_amdgcn_s_setprio(0);
    }
#undef STAGE

    // epilogue: relu(s2 - 2*acc + w2), float4 over 4 consecutive m (hw-contig)
#pragma unroll
    for (int m = 0; m < 4; ++m) {
        const int m_r = bm * TBM + wm + m * 16 + lg * 4;   // 4-aligned, 784%4==0
        const float4 s2v = *(const float4*)(s2 + m_r);
        const uint32_t ob  = (uint32_t)m_r / 784u;
        const uint32_t ohw = (uint32_t)m_r % 784u;
        float* obase = out + (size_t)ob * OUT_BATCH + ohw;
#pragma unroll
        for (int n = 0; n < 4; ++n) {
            const int n_o = bn * TBN + wn + n * 16 + lr;
            if (n_o < N_TOT) {
                const float wvv = w2[n_o];
                const f32x4 a = acc[m][n];
                float4 r;
                r.x = fmaxf(s2v.x - 2.f * a.x + wvv, 0.f);
                r.y = fmaxf(s2v.y - 2.f * a.y + wvv, 0.f);
                r.z = fmaxf(s2v.z - 2.f * a.z + wvv, 0.f);
                r.w = fmaxf(s2v.w - 2.f * a.w + wvv, 0.f);
                *(float4*)(obase + (size_t)n_o * HW) = r;
            }
        }
    }
}

// ---------------------------------------------------------------------------
extern "C" void kernel_launch(void* const* d_in, const int* in_sizes, int n_in,
                              void* d_out, int out_size, void* d_ws, size_t ws_size,
                              hipStream_t stream) {
    const float* in = (const float*)d_in[0];   // [32,512,28,28] fp32
    const float* w  = (const float*)d_in[1];   // [2000,512,1,1] fp32
    float* out = (float*)d_out;                // [32,2000,28,28] fp32

    const size_t offA  = 0;
    const size_t offW  = offA + (size_t)M_TOT * C_IN * sizeof(short);   // 25.7 MB
    const size_t offS2 = offW + (size_t)NPAD * C_IN * sizeof(short);    // +2.1 MB
    const size_t offW2 = offS2 + (size_t)M_TOT * sizeof(float);

    short* Abf = (short*)((char*)d_ws + offA);
    short* Wbf = (short*)((char*)d_ws + offW);
    float* s2  = (float*)((char*)d_ws + offS2);
    float* w2  = (float*)((char*)d_ws + offW2);

    prep_a_kernel<<<M_TOT / 64, 256, 0, stream>>>(in, Abf, s2);
    prep_w_kernel<<<NPAD / 4, 256, 0, stream>>>(w, Wbf, w2);

    // 196 m-tiles x 16 n-tiles = 3136 blocks, 3 resident per CU
    gemm5_kernel<<<196 * 16, 256, 0, stream>>>(Abf, Wbf, s2, w2, out);
}